// Round 10
// baseline (826.653 us; speedup 1.0000x reference)
//
#include <hip/hip_runtime.h>
#include <math.h>

#define Bb 4
#define Ll 1024
#define CSd 384
#define CPd 128
#define Hh 8
#define BL 4096
#define CAT2W 276
#define CATW 1408
#define QKVW 2208          // 512 q + 512 k + 512 v + 192 qp + 192 kp + 288 vp
#define PARTW 168          // per-row partial: o64 | og36(pad->[64,100)) | op64 | m,l
#define LDP 40             // LDS bf16 row pitch

#define S_QK 0.07216878364870322f     // 1/sqrt(3*64)
#define SQ13 0.5773502691896258f      // sqrt(1/3)
#define HW_SCALE 0.09622504486493764f // sqrt(1/108)

typedef short bf16x8 __attribute__((ext_vector_type(8)));
typedef float f32x4  __attribute__((ext_vector_type(4)));

__device__ __forceinline__ ushort f2bf(float f) {
    uint u = __float_as_uint(f);
    u += 0x7FFF + ((u >> 16) & 1);          // RNE
    return (ushort)(u >> 16);
}
__device__ __forceinline__ float bf2f(ushort h) {
    return __uint_as_float(((uint)h) << 16);
}

// ---------------------------------------------------------------------------
// convert_act: fp32 [M][K] -> bf16 hi/lo planes [M][Kpad] (pad zero-filled)
// ---------------------------------------------------------------------------
__global__ __launch_bounds__(256) void convert_act(
    const float* __restrict__ in, ushort* __restrict__ hi, ushort* __restrict__ lo,
    int K, int Kpad, int total8)
{
    const int kpd8 = Kpad >> 3;
    for (int idx = blockIdx.x * 256 + threadIdx.x; idx < total8; idx += gridDim.x * 256) {
        const int row = idx / kpd8;
        const int kc = (idx - row * kpd8) * 8;
        const float* p = in + (size_t)row * K + kc;
        float v[8];
        if (kc + 8 <= K) {
            const float4 a = *(const float4*)p, b = *(const float4*)(p + 4);
            v[0]=a.x; v[1]=a.y; v[2]=a.z; v[3]=a.w;
            v[4]=b.x; v[5]=b.y; v[6]=b.z; v[7]=b.w;
        } else {
#pragma unroll
            for (int u = 0; u < 8; ++u) v[u] = (kc + u < K) ? p[u] : 0.f;
        }
        ushort h[8], l[8];
#pragma unroll
        for (int u = 0; u < 8; ++u) {
            h[u] = f2bf(v[u]);
            l[u] = f2bf(v[u] - bf2f(h[u]));
        }
        *(bf16x8*)&hi[(size_t)row * Kpad + kc] = *(const bf16x8*)h;
        *(bf16x8*)&lo[(size_t)row * Kpad + kc] = *(const bf16x8*)l;
    }
}

// ---------------------------------------------------------------------------
// convert_wt: fp32 W [K][N] -> transposed bf16 hi/lo planes [Npad][Kpad]
// (pads zero). grid (Npad/64, Kpad/32), 256 thr.
// ---------------------------------------------------------------------------
__global__ __launch_bounds__(256) void convert_wt(
    const float* __restrict__ W, ushort* __restrict__ hi, ushort* __restrict__ lo,
    int K, int N, int Kpad)
{
    __shared__ float t[32][65];
    const int bn = blockIdx.x * 64, k0 = blockIdx.y * 32;
    const int tid = threadIdx.x;
    {
        const int n = tid & 63, kk = tid >> 6;
#pragma unroll
        for (int r = 0; r < 8; ++r) {
            const int k = k0 + r * 4 + kk;
            t[r * 4 + kk][n] = (k < K && bn + n < N) ? W[(size_t)k * N + bn + n] : 0.f;
        }
    }
    __syncthreads();
    const int n2 = tid >> 2, kc = (tid & 3) * 8;
    ushort h[8], l[8];
#pragma unroll
    for (int u = 0; u < 8; ++u) {
        const float v = t[kc + u][n2];
        h[u] = f2bf(v);
        l[u] = f2bf(v - bf2f(h[u]));
    }
    *(bf16x8*)&hi[(size_t)(bn + n2) * Kpad + k0 + kc] = *(const bf16x8*)h;
    *(bf16x8*)&lo[(size_t)(bn + n2) * Kpad + k0 + kc] = *(const bf16x8*)l;
}

// ---------------------------------------------------------------------------
// gemm_bf16: C[M,N] = A@W (+bias)(+relu). Inputs pre-converted bf16 hi/lo
// planes: A [M][Kpad] row-major, W [Npad][Kpad] (transposed). 64x64 tile,
// 4 waves 2x2, BK=32, mfma_f32_16x16x32_bf16 triple per frag. No k-guards
// (Kpad%32==0, pads zero). M%64==0; C col guard for N.
// ---------------------------------------------------------------------------
template<bool RELU, bool HASBIAS>
__global__ __launch_bounds__(256) void gemm_bf16(
    const ushort* __restrict__ Ahi, const ushort* __restrict__ Alo, int Kpad,
    const ushort* __restrict__ Whi, const ushort* __restrict__ Wlo,
    const float* __restrict__ bias,
    float* __restrict__ C, int ldc, int N)
{
    __shared__ short Ah[64][LDP], Al[64][LDP];
    __shared__ short Wh[64][LDP], Wl[64][LDP];
    const int tid = threadIdx.x;
    const int lane = tid & 63;
    const int wave = tid >> 6;
    const int qm = wave >> 1, qn = wave & 1;
    const int bm = blockIdx.y * 64, bn = blockIdx.x * 64;

    f32x4 acc[2][2];
#pragma unroll
    for (int i = 0; i < 2; ++i)
#pragma unroll
        for (int j = 0; j < 2; ++j) {
            acc[i][j][0] = 0.f; acc[i][j][1] = 0.f;
            acc[i][j][2] = 0.f; acc[i][j][3] = 0.f;
        }

    const int rsel = lane & 15;
    const int ksel = (lane >> 4) * 8;
    const int arow = tid >> 2, akc = (tid & 3) * 8;        // A stage map
    const int wcol = tid & 63, wko = (tid >> 6) * 8;       // W stage map
    const int wswz = ((wcol >> 3) & 3) << 3;

    for (int k0 = 0; k0 < Kpad; k0 += 32) {
        __syncthreads();
        *(bf16x8*)&Ah[arow][akc] = *(const bf16x8*)&Ahi[(size_t)(bm + arow) * Kpad + k0 + akc];
        *(bf16x8*)&Al[arow][akc] = *(const bf16x8*)&Alo[(size_t)(bm + arow) * Kpad + k0 + akc];
        *(bf16x8*)&Wh[wcol][wko ^ wswz] = *(const bf16x8*)&Whi[(size_t)(bn + wcol) * Kpad + k0 + wko];
        *(bf16x8*)&Wl[wcol][wko ^ wswz] = *(const bf16x8*)&Wlo[(size_t)(bn + wcol) * Kpad + k0 + wko];
        __syncthreads();

        bf16x8 afh[2], afl[2], wfh[2], wfl[2];
#pragma unroll
        for (int fr = 0; fr < 2; ++fr) {
            const int row = qm * 32 + fr * 16 + rsel;
            afh[fr] = *(const bf16x8*)&Ah[row][ksel];
            afl[fr] = *(const bf16x8*)&Al[row][ksel];
        }
#pragma unroll
        for (int fc = 0; fc < 2; ++fc) {
            const int col = qn * 32 + fc * 16 + rsel;
            const int swz = ((col >> 3) & 3) << 3;
            wfh[fc] = *(const bf16x8*)&Wh[col][ksel ^ swz];
            wfl[fc] = *(const bf16x8*)&Wl[col][ksel ^ swz];
        }
#pragma unroll
        for (int fr = 0; fr < 2; ++fr)
#pragma unroll
            for (int fc = 0; fc < 2; ++fc) {
                acc[fr][fc] = __builtin_amdgcn_mfma_f32_16x16x32_bf16(
                    afh[fr], wfh[fc], acc[fr][fc], 0, 0, 0);
                acc[fr][fc] = __builtin_amdgcn_mfma_f32_16x16x32_bf16(
                    afh[fr], wfl[fc], acc[fr][fc], 0, 0, 0);
                acc[fr][fc] = __builtin_amdgcn_mfma_f32_16x16x32_bf16(
                    afl[fr], wfh[fc], acc[fr][fc], 0, 0, 0);
            }
    }

#pragma unroll
    for (int fr = 0; fr < 2; ++fr)
#pragma unroll
        for (int fc = 0; fc < 2; ++fc) {
            const int col = bn + qn * 32 + fc * 16 + rsel;
            if (col < N) {
                const float bv = HASBIAS ? bias[col] : 0.f;
#pragma unroll
                for (int r = 0; r < 4; ++r) {
                    const int row = bm + qm * 32 + fr * 16 + (lane >> 4) * 4 + r;
                    float x = acc[fr][fc][r] + bv;
                    if (RELU) x = fmaxf(x, 0.f);
                    C[(size_t)row * ldc + col] = x;
                }
            }
        }
}

// ---------------------------------------------------------------------------
// weight packing
// ---------------------------------------------------------------------------
__global__ __launch_bounds__(256) void pack_qkv(
    const float* __restrict__ Wq, const float* __restrict__ Wk,
    const float* __restrict__ Wv, const float* __restrict__ Wqp,
    const float* __restrict__ Wkp, const float* __restrict__ Wvp,
    float* __restrict__ Wp)
{
    const int k = blockIdx.x;
    float* dst = Wp + (size_t)k * QKVW;
    for (int n = threadIdx.x; n < QKVW; n += 256) {
        float v;
        if      (n < 512)  v = Wq [(size_t)k*512 + n];
        else if (n < 1024) v = Wk [(size_t)k*512 + n - 512];
        else if (n < 1536) v = Wv [(size_t)k*512 + n - 1024];
        else if (n < 1728) v = Wqp[(size_t)k*192 + n - 1536];
        else if (n < 1920) v = Wkp[(size_t)k*192 + n - 1728];
        else               v = Wvp[(size_t)k*288 + n - 1920];
        dst[n] = v;
    }
}

__global__ __launch_bounds__(256) void pack_f12(
    const float* __restrict__ Wf1, const float* __restrict__ Wf2,
    const float* __restrict__ bf1, const float* __restrict__ bf2,
    float* __restrict__ Wp, float* __restrict__ bp)
{
    const int k = blockIdx.x;
    float* dst = Wp + (size_t)k * 512;
    for (int n = threadIdx.x; n < 512; n += 256)
        dst[n] = (n < 256) ? Wf1[(size_t)k*256 + n] : Wf2[(size_t)k*256 + n - 256];
    if (k == 0)
        for (int n = threadIdx.x; n < 512; n += 256)
            bp[n] = (n < 256) ? bf1[n] : bf2[n - 256];
}

// ---------------------------------------------------------------------------
// edge features: cat2[:,128:256]=pos-emb, [256:276]=neighbor distances
// ---------------------------------------------------------------------------
__global__ __launch_bounds__(128) void edge_feat(
    const float* __restrict__ trans, float* __restrict__ cat2)
{
    const int row = blockIdx.x;
    const int l = row & (Ll - 1);
    const int b = row >> 10;
    const int tid = threadIdx.x;
    {
        float v;
        if (tid < 64) {
            const float fr = __expf(-9.210340371976184f / 64.f * (float)tid);
            v = sinf((float)l * fr);
        } else {
            const float fr = __expf(-9.210340371976184f / 64.f * (float)(tid - 64));
            v = cosf((float)l * fr);
        }
        cat2[(size_t)row * CAT2W + 128 + tid] = v;
    }
    if (tid < 20) {
        const int off = (tid < 10) ? (tid - 10) : (tid - 9);
        int j = l + off;
        j = j < 0 ? 0 : (j > Ll - 1 ? Ll - 1 : j);
        const float dx = trans[(size_t)(b*Ll + j)*3 + 0] - trans[(size_t)row*3 + 0];
        const float dy = trans[(size_t)(b*Ll + j)*3 + 1] - trans[(size_t)row*3 + 1];
        const float dz = trans[(size_t)(b*Ll + j)*3 + 2] - trans[(size_t)row*3 + 2];
        cat2[(size_t)row * CAT2W + 256 + tid] = sqrtf(dx*dx + dy*dy + dz*dz);
    }
}

// ---------------------------------------------------------------------------
// z-derived factors from packed z12 [BL][512]
// ---------------------------------------------------------------------------
__global__ __launch_bounds__(256) void z_derive(
    const float* __restrict__ z12, const float* __restrict__ mask,
    const float* __restrict__ Wb1, const float* __restrict__ Wb2,
    const float* __restrict__ Wz1, const float* __restrict__ Wz2,
    float* __restrict__ bfi, float* __restrict__ bfj,
    float* __restrict__ zv1, float* __restrict__ zv2)
{
    __shared__ float zsh[512];
    const int row = blockIdx.x;
    const int tid = threadIdx.x;
    for (int idx = tid; idx < 512; idx += 256)
        zsh[idx] = z12[(size_t)row * 512 + idx];
    __syncthreads();
    const float mv = mask[row];
    if (tid < 16) {
        const int r = tid >> 3, h = tid & 7;
        float acc = 0.f;
        for (int c = 0; c < 128; ++c) acc = fmaf(zsh[r*128 + c], Wb1[c*8 + h], acc);
        bfi[(size_t)row*16 + r*8 + h] = mv * acc;
    } else if (tid < 80) {
        const int o = tid - 16, r = o >> 5, dd = o & 31;
        float acc = 0.f;
        for (int c = 0; c < 128; ++c) acc = fmaf(zsh[r*128 + c], Wz1[c*32 + dd], acc);
        zv1[(size_t)row*64 + r*32 + dd] = mv * acc;
    } else if (tid < 96) {
        const int o = tid - 80, r = o >> 3, h = o & 7;
        float acc = 0.f;
        for (int c = 0; c < 128; ++c) acc = fmaf(zsh[256 + r*128 + c], Wb2[c*8 + h], acc);
        bfj[(size_t)row*16 + r*8 + h] = mv * acc;
    } else if (tid < 160) {
        const int o = tid - 96, r = o >> 5, dd = o & 31;
        float acc = 0.f;
        for (int c = 0; c < 128; ++c) acc = fmaf(zsh[256 + r*128 + c], Wz2[c*32 + dd], acc);
        zv2[(size_t)row*64 + r*32 + dd] = mv * acc;
    }
}

// ---------------------------------------------------------------------------
// to_global on packed qkv (qp@1536, kp@1728, vp@1920), q2/k2 [B,H,L]
// ---------------------------------------------------------------------------
__global__ __launch_bounds__(256) void to_global_k(
    const float* __restrict__ rots, const float* __restrict__ trans,
    float* __restrict__ qkv, float* __restrict__ q2, float* __restrict__ k2)
{
    const int row = blockIdx.x;
    const int b = row >> 10, l = row & (Ll - 1);
    const int tid = threadIdx.x;
    __shared__ float sq[64], sk[64];
    float R[9], tn[3];
#pragma unroll
    for (int i = 0; i < 9; ++i) R[i] = rots[(size_t)row*9 + i];
#pragma unroll
    for (int i = 0; i < 3; ++i) tn[i] = trans[(size_t)row*3 + i] * 0.1f;

    float* base = nullptr;
    float* sq2 = nullptr;
    if (tid < 64)       { base = qkv + (size_t)row*QKVW + 1536 + tid*3;        sq2 = &sq[tid]; }
    else if (tid < 128) { base = qkv + (size_t)row*QKVW + 1728 + (tid-64)*3;   sq2 = &sk[tid-64]; }
    else if (tid < 224) { base = qkv + (size_t)row*QKVW + 1920 + (tid-128)*3; }
    if (base) {
        const float px = base[0], py = base[1], pz = base[2];
        const float gx = fmaf(R[0],px, fmaf(R[1],py, fmaf(R[2],pz, tn[0])));
        const float gy = fmaf(R[3],px, fmaf(R[4],py, fmaf(R[5],pz, tn[1])));
        const float gz = fmaf(R[6],px, fmaf(R[7],py, fmaf(R[8],pz, tn[2])));
        base[0] = gx; base[1] = gy; base[2] = gz;
        if (sq2) *sq2 = gx*gx + gy*gy + gz*gz;
    }
    __syncthreads();
    if (tid < 8) {
        float s2 = 0.f;
#pragma unroll
        for (int p = 0; p < 8; ++p) s2 += sq[tid*8 + p];
        q2[((size_t)b*Hh + tid)*Ll + l] = s2;
    } else if (tid < 16) {
        const int h = tid - 8;
        float s2 = 0.f;
#pragma unroll
        for (int p = 0; p < 8; ++p) s2 += sk[h*8 + p];
        k2[((size_t)b*Hh + h)*Ll + l] = s2;
    }
}

// ---------------------------------------------------------------------------
// flash IPA v4: 4 rows per group, j-split x2 (unchanged from round 7).
// ---------------------------------------------------------------------------
__global__ __launch_bounds__(256, 2) void flash_ipa4(
    const float* __restrict__ qkv,
    const float* __restrict__ q2g, const float* __restrict__ k2g,
    const float* __restrict__ bfi, const float* __restrict__ bfj,
    const float* __restrict__ zv2,
    const float* __restrict__ maskg, const float* __restrict__ gamma,
    float* __restrict__ part)
{
    __shared__ float sk[32][64];
    __shared__ float skp[32][32];
    __shared__ float sv[32][64];
    __shared__ float svp[32][36];
    __shared__ float szv[32][64];
    __shared__ float4 sjs[32];

    const int tid = threadIdx.x;
    const int t = tid & 7, g = tid >> 3;
    const int jh = blockIdx.x & 1;
    const int it = (blockIdx.x >> 1) & 7;
    const int bh = blockIdx.x >> 4;
    const int b = bh >> 3, h = bh & 7;
    const int i0 = it * 128 + g;

    const float hw = log1pf(__expf(gamma[h])) * HW_SCALE;
    const float nh = -0.5f * hw;

    float qa[4][8], qp[4][4], cI[4], bfa[4], bfb[4];
#pragma unroll
    for (int rr = 0; rr < 4; ++rr) {
        const int row = b * Ll + i0 + 32 * rr;
        const float* p0 = qkv + (size_t)row * QKVW + h * 64 + 8 * t;
        const float4 a0 = *(const float4*)p0, a1 = *(const float4*)(p0 + 4);
        qa[rr][0]=a0.x*S_QK; qa[rr][1]=a0.y*S_QK; qa[rr][2]=a0.z*S_QK; qa[rr][3]=a0.w*S_QK;
        qa[rr][4]=a1.x*S_QK; qa[rr][5]=a1.y*S_QK; qa[rr][6]=a1.z*S_QK; qa[rr][7]=a1.w*S_QK;
        float4 e0 = make_float4(0,0,0,0);
        if (t < 6)
            e0 = *(const float4*)(qkv + (size_t)row*QKVW + 1536 + h*24 + 4*t);
        qp[rr][0]=e0.x*hw; qp[rr][1]=e0.y*hw; qp[rr][2]=e0.z*hw; qp[rr][3]=e0.w*hw;
        cI[rr]  = nh * q2g[((size_t)b*Hh + h)*Ll + i0 + 32*rr];
        bfa[rr] = SQ13 * bfi[(size_t)row*16 + h];
        bfb[rr] = SQ13 * bfi[(size_t)row*16 + 8 + h];
    }

    float o[4][8] = {}, og[4][5] = {}, op[4][8] = {};
    float m[4] = {-1e30f,-1e30f,-1e30f,-1e30f}, l[4] = {};

    for (int jt = jh * 16; jt < jh * 16 + 16; ++jt) {
        const int rowj = b * Ll + jt * 32;
        __syncthreads();
#pragma unroll
        for (int r = 0; r < 2; ++r) {
            const int idx = tid + 256 * r;
            const int jj = idx >> 4, c4 = idx & 15;
            const float* src = qkv + (size_t)(rowj + jj) * QKVW;
            *(float4*)&sk[jj][c4*4]  = *(const float4*)(src + 512  + h*64 + c4*4);
            *(float4*)&sv[jj][c4*4]  = *(const float4*)(src + 1024 + h*64 + c4*4);
            *(float4*)&szv[jj][c4*4] = *(const float4*)(zv2 + (size_t)(rowj + jj)*64 + c4*4);
        }
        {
            const int jj = tid >> 3, c4 = tid & 7;
            float4 v4 = make_float4(0,0,0,0);
            if (c4 < 6)
                v4 = *(const float4*)(qkv + (size_t)(rowj + jj)*QKVW + 1728 + h*24 + c4*4);
            *(float4*)&skp[jj][c4*4] = v4;
        }
#pragma unroll
        for (int r = 0; r < 2; ++r) {
            const int idx = tid + 256 * r;
            if (idx < 288) {
                const int jj = idx / 9, c4 = idx % 9;
                *(float4*)&svp[jj][c4*4] =
                    *(const float4*)(qkv + (size_t)(rowj + jj)*QKVW + 1920 + h*36 + c4*4);
            }
        }
        if (tid < 32) {
            const int j = jt * 32 + tid;
            sjs[tid] = make_float4(
                k2g[((size_t)b*Hh + h)*Ll + j],
                (maskg[(size_t)b*Ll + j] - 1.f) * 1e9f,
                bfj[(size_t)(b*Ll + j)*16 + h],
                bfj[(size_t)(b*Ll + j)*16 + 8 + h]);
        }
        __syncthreads();

        for (int jj = 0; jj < 32; ++jj) {
            const float4 ka = *(const float4*)&sk[jj][8*t];
            const float4 kb = *(const float4*)&sk[jj][8*t + 4];
            const float4 kp4 = *(const float4*)&skp[jj][4*t];
            const float kv[8] = {ka.x,ka.y,ka.z,ka.w,kb.x,kb.y,kb.z,kb.w};
            const float kpv[4] = {kp4.x,kp4.y,kp4.z,kp4.w};
            float d[4];
#pragma unroll
            for (int rr = 0; rr < 4; ++rr) {
                float dd = 0.f;
#pragma unroll
                for (int u = 0; u < 8; ++u) dd = fmaf(qa[rr][u], kv[u], dd);
#pragma unroll
                for (int u = 0; u < 4; ++u) dd = fmaf(qp[rr][u], kpv[u], dd);
                d[rr] = dd;
            }
#pragma unroll
            for (int rr = 0; rr < 4; ++rr) {
                d[rr] += __shfl_xor(d[rr], 1, 64);
                d[rr] += __shfl_xor(d[rr], 2, 64);
                d[rr] += __shfl_xor(d[rr], 4, 64);
            }
            const float4 js = sjs[jj];

            const float4 va = *(const float4*)&sv[jj][8*t];
            const float4 vb = *(const float4*)&sv[jj][8*t + 4];
            const float vv[8] = {va.x,va.y,va.z,va.w,vb.x,vb.y,vb.z,vb.w};
            const float4 vpa = *(const float4*)&svp[jj][4*t];
            const float vpv[4] = {vpa.x,vpa.y,vpa.z,vpa.w};
            const float vpe = svp[jj][32 + (t & 3)];
            const float vpes = (t < 4) ? vpe : 0.f;
            const float4 za = *(const float4*)&szv[jj][8*t];
            const float4 zb = *(const float4*)&szv[jj][8*t + 4];
            const float zz[8] = {za.x,za.y,za.z,za.w,zb.x,zb.y,zb.z,zb.w};

#pragma unroll
            for (int rr = 0; rr < 4; ++rr) {
                const float lg = d[rr] +
                    fmaf(bfa[rr], js.z, fmaf(bfb[rr], js.w, fmaf(nh, js.x, js.y + cI[rr])));
                if (lg > m[rr]) {
                    const float f = __expf(m[rr] - lg); m[rr] = lg; l[rr] *= f;
#pragma unroll
                    for (int u = 0; u < 8; ++u) o[rr][u] *= f;
#pragma unroll
                    for (int u = 0; u < 5; ++u) og[rr][u] *= f;
#pragma unroll
                    for (int u = 0; u < 8; ++u) op[rr][u] *= f;
                }
                const float p = __expf(lg - m[rr]); l[rr] += p;
#pragma unroll
                for (int u = 0; u < 8; ++u) o[rr][u] = fmaf(p, vv[u], o[rr][u]);
#pragma unroll
                for (int u = 0; u < 4; ++u) og[rr][u] = fmaf(p, vpv[u], og[rr][u]);
                og[rr][4] = fmaf(p, vpes, og[rr][4]);
#pragma unroll
                for (int u = 0; u < 8; ++u) op[rr][u] = fmaf(p, zz[u], op[rr][u]);
            }
        }
    }

#pragma unroll
    for (int rr = 0; rr < 4; ++rr) {
        float* pr = part + ((size_t)(bh * 2 + jh) * Ll + i0 + 32 * rr) * PARTW;
        *(float4*)&pr[8*t]     = make_float4(o[rr][0], o[rr][1], o[rr][2], o[rr][3]);
        *(float4*)&pr[8*t + 4] = make_float4(o[rr][4], o[rr][5], o[rr][6], o[rr][7]);
        *(float4*)&pr[64 + 4*t] = make_float4(og[rr][0], og[rr][1], og[rr][2], og[rr][3]);
        if (t < 4) pr[96 + t] = og[rr][4];
        *(float4*)&pr[100 + 8*t]     = make_float4(op[rr][0], op[rr][1], op[rr][2], op[rr][3]);
        *(float4*)&pr[100 + 8*t + 4] = make_float4(op[rr][4], op[rr][5], op[rr][6], op[rr][7]);
        if (t == 0) { pr[164] = m[rr]; pr[165] = l[rr]; }
    }
}

// ---------------------------------------------------------------------------
// combine: merge the two j-halves, normalize, apply zv1, rotate og back.
// ---------------------------------------------------------------------------
__global__ __launch_bounds__(256) void combine_ipa(
    const float* __restrict__ part,
    const float* __restrict__ zv1,
    const float* __restrict__ rots, const float* __restrict__ trans,
    float* __restrict__ cat)
{
    __shared__ float sog[64][36];
    const int tid = threadIdx.x;
    const int t = tid & 7, g = tid >> 3;
    const int it = blockIdx.x & 15;
    const int bh = blockIdx.x >> 4;
    const int b = bh >> 3, h = bh & 7;
    const int i0 = it * 64 + g;

#pragma unroll
    for (int rr = 0; rr < 2; ++rr) {
        const int i = i0 + rr * 32;
        const int row = b * Ll + i;
        const float* pA = part + ((size_t)(bh * 2 + 0) * Ll + i) * PARTW;
        const float* pB = part + ((size_t)(bh * 2 + 1) * Ll + i) * PARTW;
        const float mA = pA[164], mB = pB[164];
        const float m = fmaxf(mA, mB);
        const float wA = __expf(mA - m), wB = __expf(mB - m);
        const float l = fmaf(wA, pA[165], wB * pB[165]);
        const float sA = wA / l, sB = wB / l;

        float* crow = cat + (size_t)row * CATW;
        {
            const float4 a0 = *(const float4*)&pA[8*t];
            const float4 a1 = *(const float4*)&pA[8*t + 4];
            const float4 b0 = *(const float4*)&pB[8*t];
            const float4 b1 = *(const float4*)&pB[8*t + 4];
            *(float4*)&crow[h*64 + 8*t] = make_float4(
                fmaf(sA, a0.x, sB * b0.x), fmaf(sA, a0.y, sB * b0.y),
                fmaf(sA, a0.z, sB * b0.z), fmaf(sA, a0.w, sB * b0.w));
            *(float4*)&crow[h*64 + 8*t + 4] = make_float4(
                fmaf(sA, a1.x, sB * b1.x), fmaf(sA, a1.y, sB * b1.y),
                fmaf(sA, a1.z, sB * b1.z), fmaf(sA, a1.w, sB * b1.w));
        }
        {
            const float4 a0 = *(const float4*)&pA[100 + 8*t];
            const float4 a1 = *(const float4*)&pA[100 + 8*t + 4];
            const float4 b0 = *(const float4*)&pB[100 + 8*t];
            const float4 b1 = *(const float4*)&pB[100 + 8*t + 4];
            const float4 z0 = *(const float4*)&zv1[(size_t)row*64 + 8*t];
            const float4 z1 = *(const float4*)&zv1[(size_t)row*64 + 8*t + 4];
            *(float4*)&crow[896 + h*64 + 8*t] = make_float4(
                z0.x * fmaf(sA, a0.x, sB * b0.x), z0.y * fmaf(sA, a0.y, sB * b0.y),
                z0.z * fmaf(sA, a0.z, sB * b0.z), z0.w * fmaf(sA, a0.w, sB * b0.w));
            *(float4*)&crow[896 + h*64 + 8*t + 4] = make_float4(
                z1.x * fmaf(sA, a1.x, sB * b1.x), z1.y * fmaf(sA, a1.y, sB * b1.y),
                z1.z * fmaf(sA, a1.z, sB * b1.z), z1.w * fmaf(sA, a1.w, sB * b1.w));
        }
        {
            const float4 a0 = *(const float4*)&pA[64 + 4*t];
            const float4 b0 = *(const float4*)&pB[64 + 4*t];
            sog[g + rr*32][4*t + 0] = fmaf(sA, a0.x, sB * b0.x);
            sog[g + rr*32][4*t + 1] = fmaf(sA, a0.y, sB * b0.y);
            sog[g + rr*32][4*t + 2] = fmaf(sA, a0.z, sB * b0.z);
            sog[g + rr*32][4*t + 3] = fmaf(sA, a0.w, sB * b0.w);
            if (t < 4)
                sog[g + rr*32][32 + t] = fmaf(sA, pA[96 + t], sB * pB[96 + t]);
        }
    }
    __syncthreads();
    for (int idx = tid; idx < 64 * 12; idx += 256) {
        const int ri = idx / 12, p = idx % 12;
        const int rowi = b * Ll + it * 64 + ri;
        const float ox = sog[ri][p*3 + 0] - trans[(size_t)rowi*3 + 0] * 0.1f;
        const float oy = sog[ri][p*3 + 1] - trans[(size_t)rowi*3 + 1] * 0.1f;
        const float oz = sog[ri][p*3 + 2] - trans[(size_t)rowi*3 + 2] * 0.1f;
        const float* R = rots + (size_t)rowi * 9;
        const float opx = fmaf(R[0], ox, fmaf(R[3], oy, R[6] * oz));
        const float opy = fmaf(R[1], ox, fmaf(R[4], oy, R[7] * oz));
        const float opz = fmaf(R[2], ox, fmaf(R[5], oy, R[8] * oz));
        const size_t base = (size_t)rowi * CATW + 512 + h*36 + p*3;
        cat[base + 0] = opx; cat[base + 1] = opy; cat[base + 2] = opz;
        cat[(size_t)rowi * CATW + 800 + h*12 + p] =
            sqrtf(opx*opx + opy*opy + opz*opz + 1e-8f);
    }
}

// ---------------------------------------------------------------------------
__global__ __launch_bounds__(384) void add_ln(
    const float* __restrict__ x, const float* __restrict__ y,
    const float* __restrict__ gw, const float* __restrict__ bw,
    float* __restrict__ out)
{
    __shared__ float red[6];
    const int row = blockIdx.x;
    const int c = threadIdx.x;
    const float v = x[(size_t)row*CSd + c] + y[(size_t)row*CSd + c];
    float s = v;
#pragma unroll
    for (int off = 32; off; off >>= 1) s += __shfl_down(s, off, 64);
    if ((c & 63) == 0) red[c >> 6] = s;
    __syncthreads();
    float mean = 0.f;
#pragma unroll
    for (int w = 0; w < 6; ++w) mean += red[w];
    mean *= (1.f / CSd);
    __syncthreads();
    const float d = v - mean;
    float sq = d * d;
#pragma unroll
    for (int off = 32; off; off >>= 1) sq += __shfl_down(sq, off, 64);
    if ((c & 63) == 0) red[c >> 6] = sq;
    __syncthreads();
    float var = 0.f;
#pragma unroll
    for (int w = 0; w < 6; ++w) var += red[w];
    var *= (1.f / CSd);
    out[(size_t)row*CSd + c] = d * rsqrtf(var + 1e-5f) * gw[c] + bw[c];
}

__global__ __launch_bounds__(64) void backbone(
    const float* __restrict__ s2, const float* __restrict__ Wbb,
    const float* __restrict__ bbb, const float* __restrict__ rots,
    const float* __restrict__ trans,
    float* __restrict__ outR, float* __restrict__ outT)
{
    const int row = blockIdx.x;
    const int t = threadIdx.x;
    float part[6] = {};
    for (int c = t; c < CSd; c += 64) {
        const float sv = s2[(size_t)row*CSd + c];
#pragma unroll
        for (int j = 0; j < 6; ++j) part[j] = fmaf(sv, Wbb[c*6 + j], part[j]);
    }
#pragma unroll
    for (int j = 0; j < 6; ++j) {
#pragma unroll
        for (int off = 32; off; off >>= 1) part[j] += __shfl_down(part[j], off, 64);
    }
    if (t == 0) {
        float u[6];
#pragma unroll
        for (int j = 0; j < 6; ++j) u[j] = part[j] + bbb[j];
        const float inv = 1.f / sqrtf(1.f + u[0]*u[0] + u[1]*u[1] + u[2]*u[2]);
        const float w = inv, x = u[0]*inv, y = u[1]*inv, z = u[2]*inv;
        const float Ru[9] = {
            1.f - 2.f*(y*y + z*z), 2.f*(x*y - w*z), 2.f*(x*z + w*y),
            2.f*(x*y + w*z), 1.f - 2.f*(x*x + z*z), 2.f*(y*z - w*x),
            2.f*(x*z - w*y), 2.f*(y*z + w*x), 1.f - 2.f*(x*x + y*y)};
        float R[9];
#pragma unroll
        for (int i2 = 0; i2 < 9; ++i2) R[i2] = rots[(size_t)row*9 + i2];
#pragma unroll
        for (int xi = 0; xi < 3; ++xi)
#pragma unroll
            for (int zi = 0; zi < 3; ++zi)
                outR[(size_t)row*9 + xi*3 + zi] =
                    fmaf(R[xi*3+0], Ru[0+zi],
                    fmaf(R[xi*3+1], Ru[3+zi], R[xi*3+2] * Ru[6+zi]));
#pragma unroll
        for (int xi = 0; xi < 3; ++xi)
            outT[(size_t)row*3 + xi] =
                fmaf(R[xi*3+0], u[3],
                fmaf(R[xi*3+1], u[4], R[xi*3+2] * u[5])) +
                trans[(size_t)row*3 + xi];
    }
}

// ---------------------------------------------------------------------------
extern "C" void kernel_launch(void* const* d_in, const int* in_sizes, int n_in,
                              void* d_out, int out_size, void* d_ws, size_t ws_size,
                              hipStream_t stream)
{
    const float* s      = (const float*)d_in[0];
    const float* trans  = (const float*)d_in[1];
    const float* rots   = (const float*)d_in[2];
    const float* mask   = (const float*)d_in[3];
    const float* We_s   = (const float*)d_in[4];
    const float* be_s   = (const float*)d_in[5];
    const float* We_mlp = (const float*)d_in[6];
    const float* be_mlp = (const float*)d_in[7];
    const float* Wf1    = (const float*)d_in[8];
    const float* bf1    = (const float*)d_in[9];
    const float* Wf2    = (const float*)d_in[10];
    const float* bf2    = (const float*)d_in[11];
    const float* Wq     = (const float*)d_in[12];
    const float* Wk     = (const float*)d_in[13];
    const float* Wv     = (const float*)d_in[14];
    const float* Wqp    = (const float*)d_in[15];
    const float* Wkp    = (const float*)d_in[16];
    const float* Wvp    = (const float*)d_in[17];
    const float* gamma  = (const float*)d_in[18];
    const float* Wb1    = (const float*)d_in[19];
    const float* Wb2    = (const float*)d_in[20];
    const float* Wz1    = (const float*)d_in[21];
    const float* Wz2    = (const float*)d_in[22];
    const float* Wout   = (const float*)d_in[23];
    const float* bout   = (const float*)d_in[24];
    const float* ln1_g  = (const float*)d_in[25];
    const float* ln1_b  = (const float*)d_in[26];
    const float* Wt1    = (const float*)d_in[27];
    const float* bt1    = (const float*)d_in[28];
    const float* Wt2    = (const float*)d_in[29];
    const float* bt2    = (const float*)d_in[30];
    const float* Wt3    = (const float*)d_in[31];
    const float* bt3    = (const float*)d_in[32];
    const float* ln2_g  = (const float*)d_in[33];
    const float* ln2_b  = (const float*)d_in[34];
    const float* Wbb    = (const float*)d_in[35];
    const float* bbb    = (const float*)d_in[36];

    float* ws = (float*)d_ws;
    size_t off = 0;
    auto alloc = [&](size_t n) { float* p = ws + off; off += n; return p; };
    float* cat2  = alloc((size_t)BL * CAT2W);
    float* hmid  = alloc((size_t)BL * 128);
    float* z12   = alloc((size_t)BL * 512);
    float* bfi   = alloc((size_t)BL * 16);
    float* bfj   = alloc((size_t)BL * 16);
    float* zv1   = alloc((size_t)BL * 64);
    float* zv2   = alloc((size_t)BL * 64);
    float* qkv   = alloc((size_t)BL * QKVW);
    float* q2    = alloc((size_t)BL * 8);
    float* k2    = alloc((size_t)BL * 8);
    float* cat   = alloc((size_t)BL * CATW);
    float* tmp1  = alloc((size_t)BL * CSd);
    float* s1    = alloc((size_t)BL * CSd);
    float* WpkF  = alloc((size_t)CSd * QKVW);
    float* Wf12F = alloc((size_t)128 * 512);
    float* bf12  = alloc(512);
    float* partb = alloc((size_t)32 * 2 * Ll * PARTW);   // 44 MB j-split partials
    // weight bf16 planes (hi|lo interleaved as 2 consecutive planes)
    auto allocU = [&](size_t nu) { ushort* p = (ushort*)(ws + off); off += (nu + 1) / 2; return p; };
    ushort* WTes = allocU((size_t)128 * 384 * 2);
    ushort* WTem = allocU((size_t)128 * 288 * 2);
    ushort* WTf  = allocU((size_t)512 * 128 * 2);
    ushort* WTpk = allocU((size_t)2240 * 384 * 2);
    ushort* WTo  = allocU((size_t)384 * 1408 * 2);
    ushort* WTt1 = allocU((size_t)384 * 384 * 2);
    ushort* WTt2 = allocU((size_t)384 * 384 * 2);
    ushort* WTt3 = allocU((size_t)384 * 384 * 2);

    // activation planes: alias dead regions (all stream-ordered)
    ushort* sp    = (ushort*)tmp1;                          // live steps 3..10; tmp1 written later
    ushort* cat2p = (ushort*)cat;                           // live 6..7; cat written at combine
    ushort* hmidp = (ushort*)(cat + (size_t)BL * 288);      // live 8..9
    ushort* catp  = (ushort*)partb;                         // live 11..12; partb dead after combine
    ushort* s1p   = (ushort*)tmp1;                          // live 13..14; tmp1 dead after add_ln
    ushort* h1p   = (ushort*)(partb + (size_t)BL * 1408);   // live 15..16
    ushort* h2p   = (ushort*)(partb + (size_t)BL * 1792);   // live 17..18
    float* h1   = z12;     // z12 dead after z_derive
    float* h2b  = qkv;     // qkv dead after flash
    float* tmp2 = tmp1;    // s1p dead after h1 gemm

    float* outS = (float*)d_out;
    float* outR = outS + (size_t)BL * CSd;
    float* outT = outR + (size_t)BL * 9;

    auto cagrid = [](int total8) { int g = (total8 + 255) / 256; return g > 2048 ? 2048 : g; };

    pack_qkv<<<dim3(CSd), dim3(256), 0, stream>>>(Wq, Wk, Wv, Wqp, Wkp, Wvp, WpkF);
    pack_f12<<<dim3(128), dim3(256), 0, stream>>>(Wf1, Wf2, bf1, bf2, Wf12F, bf12);

    // weight conversion (transpose to [Npad][Kpad] bf16 hi/lo)
    convert_wt<<<dim3(2, 12),  dim3(256), 0, stream>>>(We_s,  WTes, WTes + (size_t)128*384,  CSd,   128,  384);
    convert_wt<<<dim3(2, 9),   dim3(256), 0, stream>>>(We_mlp,WTem, WTem + (size_t)128*288,  CAT2W, 128,  288);
    convert_wt<<<dim3(8, 4),   dim3(256), 0, stream>>>(Wf12F, WTf,  WTf  + (size_t)512*128,  128,   512,  128);
    convert_wt<<<dim3(35, 12), dim3(256), 0, stream>>>(WpkF,  WTpk, WTpk + (size_t)2240*384, CSd,   QKVW, 384);
    convert_wt<<<dim3(6, 44),  dim3(256), 0, stream>>>(Wout,  WTo,  WTo  + (size_t)384*1408, CATW,  CSd,  1408);
    convert_wt<<<dim3(6, 12),  dim3(256), 0, stream>>>(Wt1,   WTt1, WTt1 + (size_t)384*384,  CSd,   CSd,  384);
    convert_wt<<<dim3(6, 12),  dim3(256), 0, stream>>>(Wt2,   WTt2, WTt2 + (size_t)384*384,  CSd,   CSd,  384);
    convert_wt<<<dim3(6, 12),  dim3(256), 0, stream>>>(Wt3,   WTt3, WTt3 + (size_t)384*384,  CSd,   CSd,  384);

    // edge embedder
    convert_act<<<dim3(cagrid(BL*48)), dim3(256), 0, stream>>>(s, sp, sp + (size_t)BL*384, CSd, 384, BL*48);
    gemm_bf16<false,true><<<dim3(2,64), dim3(256), 0, stream>>>(
        sp, sp + (size_t)BL*384, 384, WTes, WTes + (size_t)128*384, be_s, cat2, CAT2W, 128);
    edge_feat<<<dim3(BL), dim3(128), 0, stream>>>(trans, cat2);
    convert_act<<<dim3(cagrid(BL*36)), dim3(256), 0, stream>>>(cat2, cat2p, cat2p + (size_t)BL*288, CAT2W, 288, BL*36);
    gemm_bf16<true,true><<<dim3(2,64), dim3(256), 0, stream>>>(
        cat2p, cat2p + (size_t)BL*288, 288, WTem, WTem + (size_t)128*288, be_mlp, hmid, 128, 128);
    convert_act<<<dim3(cagrid(BL*16)), dim3(256), 0, stream>>>(hmid, hmidp, hmidp + (size_t)BL*128, 128, 128, BL*16);
    gemm_bf16<false,true><<<dim3(8,64), dim3(256), 0, stream>>>(
        hmidp, hmidp + (size_t)BL*128, 128, WTf, WTf + (size_t)512*128, bf12, z12, 512, 512);
    z_derive<<<dim3(BL), dim3(256), 0, stream>>>(z12, mask, Wb1, Wb2, Wz1, Wz2, bfi, bfj, zv1, zv2);

    // fused QKV + point projections
    gemm_bf16<false,false><<<dim3(35,64), dim3(256), 0, stream>>>(
        sp, sp + (size_t)BL*384, 384, WTpk, WTpk + (size_t)2240*384, nullptr, qkv, QKVW, QKVW);
    to_global_k<<<dim3(BL), dim3(256), 0, stream>>>(rots, trans, qkv, q2, k2);

    // fused IPA attention (4 rows/group, j-split x2) -> partials -> combine
    flash_ipa4<<<dim3(512), dim3(256), 0, stream>>>(
        qkv, q2, k2, bfi, bfj, zv2, mask, gamma, partb);
    combine_ipa<<<dim3(512), dim3(256), 0, stream>>>(partb, zv1, rots, trans, cat);

    // output projection + residual + LN1
    convert_act<<<dim3(cagrid(BL*176)), dim3(256), 0, stream>>>(cat, catp, catp + (size_t)BL*1408, CATW, 1408, BL*176);
    gemm_bf16<false,true><<<dim3(6,64), dim3(256), 0, stream>>>(
        catp, catp + (size_t)BL*1408, 1408, WTo, WTo + (size_t)384*1408, bout, tmp1, CSd, CSd);
    add_ln<<<dim3(BL), dim3(384), 0, stream>>>(s, tmp1, ln1_g, ln1_b, s1);

    // transition
    convert_act<<<dim3(cagrid(BL*48)), dim3(256), 0, stream>>>(s1, s1p, s1p + (size_t)BL*384, CSd, 384, BL*48);
    gemm_bf16<true,true><<<dim3(6,64), dim3(256), 0, stream>>>(
        s1p, s1p + (size_t)BL*384, 384, WTt1, WTt1 + (size_t)384*384, bt1, h1, CSd, CSd);
    convert_act<<<dim3(cagrid(BL*48)), dim3(256), 0, stream>>>(h1, h1p, h1p + (size_t)BL*384, CSd, 384, BL*48);
    gemm_bf16<true,true><<<dim3(6,64), dim3(256), 0, stream>>>(
        h1p, h1p + (size_t)BL*384, 384, WTt2, WTt2 + (size_t)384*384, bt2, h2b, CSd, CSd);
    convert_act<<<dim3(cagrid(BL*48)), dim3(256), 0, stream>>>(h2b, h2p, h2p + (size_t)BL*384, CSd, 384, BL*48);
    gemm_bf16<false,true><<<dim3(6,64), dim3(256), 0, stream>>>(
        h2p, h2p + (size_t)BL*384, 384, WTt3, WTt3 + (size_t)384*384, bt3, tmp2, CSd, CSd);
    add_ln<<<dim3(BL), dim3(384), 0, stream>>>(s1, tmp2, ln2_g, ln2_b, outS);

    // backbone update
    backbone<<<dim3(BL), dim3(64), 0, stream>>>(outS, Wbb, bbb, rots, trans, outR, outT);
}